// Round 19
// baseline (7506.454 us; speedup 1.0000x reference)
//
#include <hip/hip_runtime.h>
#include <hip/hip_bf16.h>

// ---------------------------------------------------------------------------
// CharRNN: emb -> 4x conv1d(SAME) -> concat -> GRU(256) last state.
//
// xw[b,t,:] = (beff+brec folded into MFMA acc) + sum_d EmbW[d][X[b,t+d-2]][:]
//
// R19: key insight -- the recurrence is PER-BATCH-ROW independent, so the
// row-split structure (8 blocks x 16 rows, zero inter-block comm) is right;
// R18 failed only on B-feeding (spills + 96 latency-chained L2 loads).
// Fix: stream Wh through LDS via async global_load_lds in a WAVE-LOCAL
// pipeline: wave owns 6 col-tiles; per 4KB half-tile: vmcnt(0) (waits own
// stages from last iter) -> issue 4 stages for next half-tile -> 8 dsA +
// 8 dsB (XOR-swizzled via pre-swizzled GLOBAL source, LDS linear) -> 8 MFMA.
// No barriers in the chunk loop; no B registers -> no spills.
// h in LDS (split-bf16 hi/lo, single plane); 2 barriers/step.
// Numerics identical to R18/R14: absmax 9.8e-4.
// ---------------------------------------------------------------------------

typedef float f32x4 __attribute__((ext_vector_type(4)));
typedef short s16x8 __attribute__((ext_vector_type(8)));
typedef unsigned short u16;
typedef unsigned int   u32;

// ws byte offsets
#define OFF_WC    0u         // f32  [5][64][768]
#define OFF_EMBW  983040u    // f32  [5][128][768]
#define OFF_BEFF  2949120u   // f32  [768]
#define OFF_WHP   2952192u   // bf16 [768][256] (Wh^T)
#define OFF_MODE  3345408u   // int
#define WS_NEED   3345472u

__device__ __forceinline__ float bf2f(u16 v){
  unsigned u = ((unsigned)v) << 16; return __builtin_bit_cast(float, u);
}
__device__ __forceinline__ u16 f2bf(float f){
  unsigned u = __builtin_bit_cast(unsigned, f);
  unsigned r = u + 0x7FFFu + ((u >> 16) & 1u);
  return (u16)(r >> 16);
}
__device__ __forceinline__ float ldv(const void* p, int i, int m){
  return m ? ((const float*)p)[i] : bf2f(((const u16*)p)[i]);
}

// ---- probe: detect storage dtype of emb_table ----
__global__ void k_probe(const void* __restrict__ emb, char* ws){
  const u16* w = (const u16*)emb;
  const int ln = threadIdx.x;
  bool bad = false;
  for (int j = 0; j < 8; ++j){
    u16 v = w[ln*8 + j];
    if (((v >> 7) & 0xFF) >= 0x86) bad = true;
  }
  unsigned long long m = __ballot(bad);
  if (ln == 0) *(int*)(ws + OFF_MODE) = (__popcll(m) > 4) ? 1 : 0;
}

// ---- Wc[d][e][j] = sum_br sum_c w_br[d-2+pad][e][c] * Wx[off_br+c][j] ----
__global__ void k_wc(const void* __restrict__ w2, const void* __restrict__ w3,
                     const void* __restrict__ w4, const void* __restrict__ w5,
                     const void* __restrict__ Wx, char* ws){
  const int md = *(const int*)(ws + OFF_MODE);
  const int d = blockIdx.x >> 6;
  const int e = blockIdx.x & 63;
  const int j0 = threadIdx.x;
  const void* wv[4] = {w2,w3,w4,w5};
  const int Kk[4] = {2,3,4,5}, pd[4] = {0,1,1,2};
  float a0=0.f, a1=0.f, a2=0.f;
  for (int br=0; br<4; ++br){
    int k = d - 2 + pd[br];
    if (k < 0 || k >= Kk[br]) continue;
    const int wbase  = (k*64 + e)*128;
    const int wxbase = (br*128)*768;
    for (int c=0; c<128; ++c){
      float wcv = ldv(wv[br], wbase + c, md);
      a0 += wcv * ldv(Wx, wxbase + c*768 + j0      , md);
      a1 += wcv * ldv(Wx, wxbase + c*768 + j0 + 256, md);
      a2 += wcv * ldv(Wx, wxbase + c*768 + j0 + 512, md);
    }
  }
  float* o = (float*)(ws + OFF_WC) + (d*64 + e)*768;
  o[j0] = a0; o[j0+256] = a1; o[j0+512] = a2;
}

// ---- beff[j] = b_in[j] + sum_br sum_c b_br[c]*Wx[off+c][j] ----
__global__ void k_beff(const void* __restrict__ b2, const void* __restrict__ b3,
                       const void* __restrict__ b4, const void* __restrict__ b5,
                       const void* __restrict__ Wx, const void* __restrict__ bin,
                       char* ws){
  const int md = *(const int*)(ws + OFF_MODE);
  int j = blockIdx.x*256 + threadIdx.x;
  if (j >= 768) return;
  const void* bv[4] = {b2,b3,b4,b5};
  float acc = ldv(bin, j, md);
  for (int br=0; br<4; ++br)
    for (int c=0; c<128; ++c)
      acc += ldv(bv[br], c, md) * ldv(Wx, (br*128 + c)*768 + j, md);
  ((float*)(ws + OFF_BEFF))[j] = acc;
}

// ---- EmbW[d][ch][j] = sum_e emb[ch][e] * Wc[d][e][j]  (f32 out) ----
__global__ void k_embw(const void* __restrict__ emb, char* ws){
  const int md = *(const int*)(ws + OFF_MODE);
  const int d = blockIdx.x >> 7, ch = blockIdx.x & 127;
  const float* wc = (const float*)(ws + OFF_WC) + d*64*768;
  float* ew = (float*)(ws + OFF_EMBW) + (size_t)(d*128 + ch)*768;
  const int j0 = threadIdx.x;
  float a0=0.f, a1=0.f, a2=0.f;
  for (int e=0; e<64; ++e){
    float ev = ldv(emb, ch*64 + e, md);
    a0 += ev*wc[e*768 + j0      ];
    a1 += ev*wc[e*768 + j0 + 256];
    a2 += ev*wc[e*768 + j0 + 512];
  }
  ew[j0] = a0; ew[j0+256] = a1; ew[j0+512] = a2;
}

// ---- whp[j][k] = Wh[k][j]  (bf16 out) ----
__global__ void k_whp(const void* __restrict__ Wh, char* ws){
  const int md = *(const int*)(ws + OFF_MODE);
  const int j = blockIdx.x, k = threadIdx.x;
  ((u16*)(ws + OFF_WHP))[j*256 + k] = f2bf(ldv(Wh, k*768 + j, md));
}

// ---- GRU: 8 blocks (one group of 16 batch rows each) x 512 thr / 8 waves ----
__launch_bounds__(512, 1)
__global__ void k_gru(const int* __restrict__ X, const void* __restrict__ brec,
                      const char* __restrict__ ws, void* __restrict__ outv){
  const int tid = threadIdx.x;
  const int w   = tid >> 6, ln = tid & 63;
  const int l15 = ln & 15, l4 = ln >> 4;
  const int g = blockIdx.x;

  const int md = *(const int*)(ws + OFF_MODE);
  const float* embw  = (const float*)(ws + OFF_EMBW);
  const float* beffp = (const float*)(ws + OFF_BEFF);
  const char*  whpB  = ws + OFF_WHP;          // byte base of Wh^T [768][256]

  __shared__ u16   Bbuf[8][2][2048];       // [wave][slot][4KB half-tile] 64KB
  __shared__ u16   hstage[2][16][264];     // [hi/lo][row][256+8]        16.9KB
  __shared__ float hwlds[16][772];         // [row][768+4]               49.4KB

  // folded bias per owned tile: col = w*96 + t*16 + l15
  float bfc[6];
  #pragma unroll
  for (int t=0; t<6; ++t){
    const int col = w*96 + t*16 + l15;
    bfc[t] = ldv(brec, col, md) + beffp[col];
  }

  // gate role: thread owns (row=tid&15, cols C*8..+8 of each gate)
  const int grow = tid & 15, C = tid >> 4;
  const int xrow = (g*16 + grow)*512;

  // zero hstage (h(0) = 0)
  {
    u32* hz = (u32*)&hstage[0][0][0];
    for (int i = tid; i < 4224; i += 512) hz[i] = 0u;
  }

  // prologue: stage half-tile 0 (tile 0, kh 0) into slot 0
  {
    u16* Bw = &Bbuf[w][0][0];
    #pragma unroll
    for (int j=0; j<4; ++j){
      const int colL = j*4 + l4;
      const size_t sb = ((size_t)(w*96 + 0*16 + colL)*256 + 0*128)*2
                        + (size_t)((l15*16) ^ ((colL & 7) << 4));
      __builtin_amdgcn_global_load_lds((const u32*)(whpB + sb),
                                       (u32*)((char*)Bw + j*1024), 16, 0, 0);
    }
  }
  float hprev[8] = {0.f,0.f,0.f,0.f,0.f,0.f,0.f,0.f};
  __syncthreads();                          // hstage zeros visible

  for (int s = 0; s < 512; ++s){

    // G) gather xw(s) into regs (taps t = s-2..s+2); completes during chunks
    f32x4 xwv[3][2];
    #pragma unroll
    for (int gg=0; gg<3; ++gg){ xwv[gg][0] = (f32x4){0,0,0,0}; xwv[gg][1] = (f32x4){0,0,0,0}; }
    #pragma unroll
    for (int d=0; d<5; ++d){
      const int t = s - 2 + d;
      if ((unsigned)t < 512u){
        const int ch = X[xrow + t] & 127;
        const float* tb = embw + (size_t)(d*128 + ch)*768 + C*8;
        #pragma unroll
        for (int gg=0; gg<3; ++gg){
          xwv[gg][0] += *(const f32x4*)(tb + gg*256);
          xwv[gg][1] += *(const f32x4*)(tb + gg*256 + 4);
        }
      }
    }

    // C) chunk loop: 12 half-tiles (tile = hI>>1, khalf = hI&1), wave-local
    f32x4 acc;
    #pragma unroll
    for (int hI=0; hI<12; ++hI){
      const int tile = hI >> 1, kh = hI & 1, slot = hI & 1;

      // wait own stages issued last iter (covers this half-tile)
      asm volatile("s_waitcnt vmcnt(0)" ::: "memory");
      __builtin_amdgcn_sched_barrier(0);

      // issue stages for next half-tile (wraps to 0 for next step)
      {
        const int nI = (hI + 1) % 12;
        const int ntile = nI >> 1, nkh = nI & 1, nslot = nI & 1;
        u16* Bw = &Bbuf[w][nslot][0];
        #pragma unroll
        for (int j=0; j<4; ++j){
          const int colL = j*4 + l4;
          const size_t sb = ((size_t)(w*96 + ntile*16 + colL)*256 + nkh*128)*2
                            + (size_t)((l15*16) ^ ((colL & 7) << 4));
          __builtin_amdgcn_global_load_lds((const u32*)(whpB + sb),
                                           (u32*)((char*)Bw + j*1024), 16, 0, 0);
        }
      }

      // MFMAs over this half-tile: 4 q-steps x (hi + lo)
      if (kh == 0) acc = (f32x4){bfc[tile], bfc[tile], bfc[tile], bfc[tile]};
      const char* Bs = (const char*)&Bbuf[w][slot][0];
      const int bswz = (l15 & 7) << 4;
      #pragma unroll
      for (int q=0; q<4; ++q){
        const int kk = kh*128 + q*32 + l4*8;
        const s16x8 ahi = *(const s16x8*)&hstage[0][l15][kk];
        const s16x8 alo = *(const s16x8*)&hstage[1][l15][kk];
        const s16x8 bf  = *(const s16x8*)(Bs + (l15*256 + ((q*64 + l4*16) ^ bswz)));
        acc = __builtin_amdgcn_mfma_f32_16x16x32_bf16(ahi, bf, acc, 0,0,0);
        acc = __builtin_amdgcn_mfma_f32_16x16x32_bf16(alo, bf, acc, 0,0,0);
      }
      if (kh == 1){
        const int col = w*96 + tile*16 + l15;
        #pragma unroll
        for (int p=0; p<4; ++p)
          hwlds[l4*4+p][col] = acc[p];
      }
    }
    __syncthreads();                          // barB: hwlds ready

    // P3) gates: thread unit (grow, C*8+j), j=0..7
    f32x4 hv[3][2];
    #pragma unroll
    for (int gg=0; gg<3; ++gg){
      hv[gg][0] = *(const f32x4*)&hwlds[grow][gg*256 + C*8];
      hv[gg][1] = *(const f32x4*)&hwlds[grow][gg*256 + C*8 + 4];
    }
    float hn[8];
    #pragma unroll
    for (int hh2=0; hh2<2; ++hh2){
      #pragma unroll
      for (int e=0; e<4; ++e){
        const int j = hh2*4 + e;
        const float z  = 1.f/(1.f + __expf(-(xwv[0][hh2][e] + hv[0][hh2][e])));
        const float r  = 1.f/(1.f + __expf(-(xwv[1][hh2][e] + hv[1][hh2][e])));
        const float pre = xwv[2][hh2][e] + r*hv[2][hh2][e];
        const float e2  = __expf(-2.f*fabsf(pre));
        const float th  = __builtin_copysignf((1.f - e2)/(1.f + e2), pre);
        hn[j] = z*hprev[j] + (1.f - z)*th;
        hprev[j] = hn[j];
      }
    }

    // P4) publish h(s+1) (split-bf16 hi/lo) or final output
    if (s == 511){
      const int i0 = (g*16 + grow)*256 + C*8;
      if (md){
        #pragma unroll
        for (int j=0; j<8; ++j) ((float*)outv)[i0 + j] = hn[j];
      } else {
        s16x8 o8;
        #pragma unroll
        for (int j=0; j<8; ++j) o8[j] = (short)f2bf(hn[j]);
        *(s16x8*)&((u16*)outv)[i0] = o8;
      }
    } else {
      s16x8 hi8, lo8;
      #pragma unroll
      for (int j=0; j<8; ++j){
        const u16 bh = f2bf(hn[j]);
        hi8[j] = (short)bh;
        lo8[j] = (short)f2bf(hn[j] - bf2f(bh));
      }
      *(s16x8*)&hstage[0][grow][C*8] = hi8;
      *(s16x8*)&hstage[1][grow][C*8] = lo8;
    }
    __syncthreads();                          // end: hstage(s+1) ready, hwlds free
  }
}

extern "C" void kernel_launch(void* const* d_in, const int* in_sizes, int n_in,
                              void* d_out, int out_size, void* d_ws, size_t ws_size,
                              hipStream_t stream){
  const int* X = (const int*)d_in[0];
  char* ws = (char*)d_ws;
  if (ws_size < WS_NEED) return;

  k_probe<<<  1,  64, 0, stream>>>(d_in[1], ws);
  k_wc   <<<320, 256, 0, stream>>>(d_in[2], d_in[4], d_in[6], d_in[8], d_in[10], ws);
  k_beff <<<  3, 256, 0, stream>>>(d_in[3], d_in[5], d_in[7], d_in[9], d_in[10], d_in[12], ws);
  k_embw <<<640, 256, 0, stream>>>(d_in[1], ws);
  k_whp  <<<768, 256, 0, stream>>>(d_in[11], ws);
  k_gru  <<<  8, 512, 0, stream>>>(X, d_in[13], ws, d_out);
}

// Round 20
// 2017.467 us; speedup vs baseline: 3.7207x; 3.7207x over previous
//
#include <hip/hip_runtime.h>
#include <hip/hip_bf16.h>

// ---------------------------------------------------------------------------
// CharRNN: emb -> 4x conv1d(SAME) -> concat -> GRU(256) last state.
//
// xw[b,t,:] = beff + sum_{d=0..4} EmbW[d][X[b,t+d-2]][:]   (f32 tables in ws)
//
// R20: RESTORE R14 VERBATIM (session best: 2009us total, k_gru 1857us).
// Rounds 15-19 attempted to beat R14's cross-XCD exchange latency via
// L2-local atomics (R15/R16), stream interleave (R17), and Wh re-streaming
// (R18/R19); all six structural gambles regressed or failed. R14's design:
//  - 32 blocks = 8 groups (16 batch rows) x 4 col-slices; Bf=48 VGPRs
//  - h exchanged via ws as (hi<<16|lo) split-bf16 u32 with step-mark in
//    bit0 (self-validating data, no flags); agent-scope relaxed atomics
//  - S1 probe: batched 2x global_load_dwordx4 sc0 sc1 + SSA-safe waitcnt
//  - 2 barriers/step; gates lane-parallel; biases via brec/beff
// ---------------------------------------------------------------------------

typedef float f32x4 __attribute__((ext_vector_type(4)));
typedef short s16x8 __attribute__((ext_vector_type(8)));
typedef int   i32x4 __attribute__((ext_vector_type(4)));
typedef unsigned short u16;
typedef unsigned int   u32;
typedef unsigned long long u64;

// ws byte offsets
#define OFF_WC    0u         // f32  [5][64][768]
#define OFF_EMBW  983040u    // f32  [5][128][768]
#define OFF_BEFF  2949120u   // f32  [768]
#define OFF_WHP   2952192u   // bf16 [768][256] (Wh^T)
#define OFF_MODE  3345408u   // int
#define OFF_HGP   3345472u   // u32 [2][8][16][256]  (par, group, row, hcol)
#define WS_NEED   3607616u

__device__ __forceinline__ float bf2f(u16 v){
  unsigned u = ((unsigned)v) << 16; return __builtin_bit_cast(float, u);
}
__device__ __forceinline__ u16 f2bf(float f){
  unsigned u = __builtin_bit_cast(unsigned, f);
  unsigned r = u + 0x7FFFu + ((u >> 16) & 1u);
  return (u16)(r >> 16);
}
__device__ __forceinline__ float ldv(const void* p, int i, int m){
  return m ? ((const float*)p)[i] : bf2f(((const u16*)p)[i]);
}

// ---- init: zero both h parity planes (mark bits 0 -> steps 0,1 validate) ----
__global__ void k_init(char* ws){
  int idx = blockIdx.x*256 + threadIdx.x;
  u32* hg = (u32*)(ws + OFF_HGP);
  if (idx < 65536) hg[idx] = 0u;
}

// ---- probe: detect storage dtype of emb_table ----
__global__ void k_probe(const void* __restrict__ emb, char* ws){
  const u16* w = (const u16*)emb;
  const int ln = threadIdx.x;
  bool bad = false;
  for (int j = 0; j < 8; ++j){
    u16 v = w[ln*8 + j];
    if (((v >> 7) & 0xFF) >= 0x86) bad = true;
  }
  unsigned long long m = __ballot(bad);
  if (ln == 0) *(int*)(ws + OFF_MODE) = (__popcll(m) > 4) ? 1 : 0;
}

// ---- Wc[d][e][j] = sum_br sum_c w_br[d-2+pad][e][c] * Wx[off_br+c][j] ----
__global__ void k_wc(const void* __restrict__ w2, const void* __restrict__ w3,
                     const void* __restrict__ w4, const void* __restrict__ w5,
                     const void* __restrict__ Wx, char* ws){
  const int md = *(const int*)(ws + OFF_MODE);
  const int d = blockIdx.x >> 6;
  const int e = blockIdx.x & 63;
  const int j0 = threadIdx.x;
  const void* wv[4] = {w2,w3,w4,w5};
  const int Kk[4] = {2,3,4,5}, pd[4] = {0,1,1,2};
  float a0=0.f, a1=0.f, a2=0.f;
  for (int br=0; br<4; ++br){
    int k = d - 2 + pd[br];
    if (k < 0 || k >= Kk[br]) continue;
    const int wbase  = (k*64 + e)*128;
    const int wxbase = (br*128)*768;
    for (int c=0; c<128; ++c){
      float wcv = ldv(wv[br], wbase + c, md);
      a0 += wcv * ldv(Wx, wxbase + c*768 + j0      , md);
      a1 += wcv * ldv(Wx, wxbase + c*768 + j0 + 256, md);
      a2 += wcv * ldv(Wx, wxbase + c*768 + j0 + 512, md);
    }
  }
  float* o = (float*)(ws + OFF_WC) + (d*64 + e)*768;
  o[j0] = a0; o[j0+256] = a1; o[j0+512] = a2;
}

// ---- beff[j] = b_in[j] + sum_br sum_c b_br[c]*Wx[off+c][j] ----
__global__ void k_beff(const void* __restrict__ b2, const void* __restrict__ b3,
                       const void* __restrict__ b4, const void* __restrict__ b5,
                       const void* __restrict__ Wx, const void* __restrict__ bin,
                       char* ws){
  const int md = *(const int*)(ws + OFF_MODE);
  int j = blockIdx.x*256 + threadIdx.x;
  if (j >= 768) return;
  const void* bv[4] = {b2,b3,b4,b5};
  float acc = ldv(bin, j, md);
  for (int br=0; br<4; ++br)
    for (int c=0; c<128; ++c)
      acc += ldv(bv[br], c, md) * ldv(Wx, (br*128 + c)*768 + j, md);
  ((float*)(ws + OFF_BEFF))[j] = acc;
}

// ---- EmbW[d][ch][j] = sum_e emb[ch][e] * Wc[d][e][j]  (f32 out) ----
__global__ void k_embw(const void* __restrict__ emb, char* ws){
  const int md = *(const int*)(ws + OFF_MODE);
  const int d = blockIdx.x >> 7, ch = blockIdx.x & 127;
  const float* wc = (const float*)(ws + OFF_WC) + d*64*768;
  float* ew = (float*)(ws + OFF_EMBW) + (size_t)(d*128 + ch)*768;
  const int j0 = threadIdx.x;
  float a0=0.f, a1=0.f, a2=0.f;
  for (int e=0; e<64; ++e){
    float ev = ldv(emb, ch*64 + e, md);
    a0 += ev*wc[e*768 + j0      ];
    a1 += ev*wc[e*768 + j0 + 256];
    a2 += ev*wc[e*768 + j0 + 512];
  }
  ew[j0] = a0; ew[j0+256] = a1; ew[j0+512] = a2;
}

// ---- whp[j][k] = Wh[k][j]  (bf16 out) ----
__global__ void k_whp(const void* __restrict__ Wh, char* ws){
  const int md = *(const int*)(ws + OFF_MODE);
  const int j = blockIdx.x, k = threadIdx.x;
  ((u16*)(ws + OFF_WHP))[j*256 + k] = f2bf(ldv(Wh, k*768 + j, md));
}

// ---- GRU: 32 blocks = 8 groups x 4 slices; 512 thr / 8 waves ----
__launch_bounds__(512, 1)
__global__ void k_gru(const int* __restrict__ X, const void* __restrict__ brec,
                      char* __restrict__ ws, void* __restrict__ outv){
  const int tid = threadIdx.x;
  const int w   = tid >> 6, ln = tid & 63;
  const int l15 = ln & 15, l4 = ln >> 4;
  const int g = blockIdx.x >> 2, r = blockIdx.x & 3;

  const int md = *(const int*)(ws + OFF_MODE);
  const float* embw = (const float*)(ws + OFF_EMBW);
  const float* beff = (const float*)(ws + OFF_BEFF);
  const u16*   whp  = (const u16*)(ws + OFF_WHP);
  u32* hgp = (u32*)(ws + OFF_HGP);

  __shared__ int   Xs[16*512];           // 32 KB
  __shared__ float xwlds[2][16][196];    // 25 KB
  __shared__ float hwp[2][16][196];      // 25 KB
  __shared__ u16   hstage[2][16][272];   // 17 KB

  for (int i = tid; i < 2048; i += 512)
    ((i32x4*)Xs)[i] = ((const i32x4*)(X + g*16*512))[i];

  // persistent Wh B-frags: wave w -> subtile w&3, K-half w>>2
  const int qs = (w >> 2) * 4;
  s16x8 Bf[3][4];
  #pragma unroll
  for (int gg=0; gg<3; ++gg){
    const int col = gg*256 + r*64 + (w&3)*16 + l15;
    #pragma unroll
    for (int qi=0; qi<4; ++qi)
      Bf[gg][qi] = *(const s16x8*)(whp + col*256 + (qs+qi)*32 + l4*8);
  }

  // gates: thread -> h-col hc = r*64+(tid&63), rows tr, tr+8
  const int c63 = tid & 63;
  const int tr  = (tid >> 6) & 7;
  const int hc  = r*64 + c63;
  const float br0 = ldv(brec,       hc, md);
  const float br1 = ldv(brec, 256 + hc, md);
  const float br2 = ldv(brec, 512 + hc, md);

  // gather: chunk ids cid1 = tid, cid2 = tid+512 (tid<256 only)
  const int row1 = tid / 48,      rem1 = tid % 48;
  const int gg1  = rem1 / 16,     cc1  = rem1 % 16;
  const int cid2 = tid + 512;
  const int row2 = cid2 / 48,     rem2 = cid2 % 48;
  const int gg2  = rem2 / 16,     cc2  = rem2 % 16;
  const bool two = (tid < 256);
  const int gcol1 = gg1*256 + r*64 + cc1*4;
  const int gcol2 = gg2*256 + r*64 + cc2*4;
  const f32x4 be1 = *(const f32x4*)(beff + gcol1);
  const f32x4 be2 = *(const f32x4*)(beff + gcol2);

  // h-stage: thread -> row srow, 8 packed cols at sc0_
  const int srow = tid >> 5, sc0_ = (tid & 31) * 8;

  __syncthreads();   // Xs staged

  // prologue: xw(0) -> xwlds[0]
  {
    f32x4 v1 = be1, v2 = be2;
    #pragma unroll
    for (int d=0; d<5; ++d){
      const int t = d - 2;
      if ((unsigned)t < 512u){
        const int ch1 = Xs[row1*512 + t] & 127;
        v1 += *(const f32x4*)(embw + (size_t)(d*128 + ch1)*768 + gcol1);
        if (two){
          const int ch2 = Xs[row2*512 + t] & 127;
          v2 += *(const f32x4*)(embw + (size_t)(d*128 + ch2)*768 + gcol2);
        }
      }
    }
    *(f32x4*)&xwlds[0][row1][gg1*64 + cc1*4] = v1;
    if (two) *(f32x4*)&xwlds[0][row2][gg2*64 + cc2*4] = v2;
  }
  float hpA = 0.f, hpB = 0.f;
  __syncthreads();

  for (int s = 0; s < 512; ++s){
    const int par = s & 1;

    // S1) spin until this thread's 8 h-words are valid. Batched probe:
    //     2x global_load_dwordx4 (sc0 sc1) + ONE waitcnt carrying the
    //     tuples as "+v" -> consumers SSA-depend on the waitcnt asm.
    const u32 em = (u32)((s >> 1) & 1);
    const u32* hb = hgp + (unsigned)par*32768u + (unsigned)g*4096u
                    + (unsigned)srow*256u + (unsigned)sc0_;
    i32x4 A, B;
    {
      int guard = 0;
      for (;;){
        asm volatile("global_load_dwordx4 %0, %2, off sc0 sc1\n\t"
                     "global_load_dwordx4 %1, %3, off sc0 sc1"
                     : "=&v"(A), "=&v"(B)
                     : "v"(hb), "v"(hb + 4)
                     : "memory");
        asm volatile("s_waitcnt vmcnt(0)" : "+v"(A), "+v"(B) :: "memory");
        __builtin_amdgcn_sched_barrier(0);
        const u32 ba = (u32)A[0] & (u32)A[1] & (u32)A[2] & (u32)A[3]
                     & (u32)B[0] & (u32)B[1] & (u32)B[2] & (u32)B[3];
        const u32 bo = (u32)A[0] | (u32)A[1] | (u32)A[2] | (u32)A[3]
                     | (u32)B[0] | (u32)B[1] | (u32)B[2] | (u32)B[3];
        const bool ok = em ? ((ba & 1u) == 1u) : ((bo & 1u) == 0u);
        if (ok || ++guard > (1<<20)) break;   // guard: fail visibly, no hang
      }
    }
    // de-interleave word = (hi<<16) | lo  -> stage planes
    {
      u32 wd[8] = {(u32)A[0],(u32)A[1],(u32)A[2],(u32)A[3],
                   (u32)B[0],(u32)B[1],(u32)B[2],(u32)B[3]};
      s16x8 hi, lo;
      #pragma unroll
      for (int j=0; j<8; ++j){ hi[j] = (short)(wd[j] >> 16); lo[j] = (short)(wd[j] & 0xFFFFu); }
      *(s16x8*)&hstage[0][srow][sc0_] = hi;
      *(s16x8*)&hstage[1][srow][sc0_] = lo;
    }
    __syncthreads();                          // barA: stage ready

    // S2) partial hw over this wave's K-half: 24 MFMAs
    f32x4 a0 = {0.f,0.f,0.f,0.f}, a1 = a0, a2 = a0;
    #pragma unroll
    for (int qi=0; qi<4; ++qi){
      const int kb = (qs+qi)*32 + l4*8;
      const s16x8 ahi = *(const s16x8*)&hstage[0][l15][kb];
      const s16x8 alo = *(const s16x8*)&hstage[1][l15][kb];
      a0 = __builtin_amdgcn_mfma_f32_16x16x32_bf16(ahi, Bf[0][qi], a0, 0,0,0);
      a1 = __builtin_amdgcn_mfma_f32_16x16x32_bf16(ahi, Bf[1][qi], a1, 0,0,0);
      a2 = __builtin_amdgcn_mfma_f32_16x16x32_bf16(ahi, Bf[2][qi], a2, 0,0,0);
      a0 = __builtin_amdgcn_mfma_f32_16x16x32_bf16(alo, Bf[0][qi], a0, 0,0,0);
      a1 = __builtin_amdgcn_mfma_f32_16x16x32_bf16(alo, Bf[1][qi], a1, 0,0,0);
      a2 = __builtin_amdgcn_mfma_f32_16x16x32_bf16(alo, Bf[2][qi], a2, 0,0,0);
    }
    {
      const int kh = w >> 2, sc = (w&3)*16 + l15;
      #pragma unroll
      for (int p=0; p<4; ++p){
        hwp[kh][l4*4+p][       sc] = a0[p];
        hwp[kh][l4*4+p][ 64 + sc] = a1[p];
        hwp[kh][l4*4+p][128 + sc] = a2[p];
      }
    }

    // S3) gather xw(s+1): issue now (L2 latency hides until gates consume)
    f32x4 n1, n2;
    if (s < 511){
      n1 = be1; n2 = be2;
      #pragma unroll
      for (int d=0; d<5; ++d){
        const int t = s - 1 + d;
        if ((unsigned)t < 512u){
          const int ch1 = Xs[row1*512 + t] & 127;
          n1 += *(const f32x4*)(embw + (size_t)(d*128 + ch1)*768 + gcol1);
          if (two){
            const int ch2 = Xs[row2*512 + t] & 127;
            n2 += *(const f32x4*)(embw + (size_t)(d*128 + ch2)*768 + gcol2);
          }
        }
      }
    }
    __syncthreads();                          // barB: hwp ready

    // S4) gates for units (tr, hc) and (tr+8, hc)
    float hnA, hnB;
    #pragma unroll
    for (int u=0; u<2; ++u){
      const int row = tr + u*8;
      const float hz = hwp[0][row][      c63] + hwp[1][row][      c63] + br0;
      const float hr = hwp[0][row][ 64 + c63] + hwp[1][row][ 64 + c63] + br1;
      const float hh = hwp[0][row][128 + c63] + hwp[1][row][128 + c63] + br2;
      const float xz = xwlds[par][row][      c63];
      const float xr = xwlds[par][row][ 64 + c63];
      const float xh = xwlds[par][row][128 + c63];
      const float hp = u ? hpB : hpA;
      const float z  = 1.f/(1.f + __expf(-(xz + hz)));
      const float rg = 1.f/(1.f + __expf(-(xr + hr)));
      const float pre = xh + rg*hh;
      const float e2  = __expf(-2.f*fabsf(pre));
      const float th  = __builtin_copysignf((1.f - e2)/(1.f + e2), pre);
      const float hn  = z*hp + (1.f - z)*th;
      if (u) hnB = hn; else hnA = hn;
    }
    hpA = hnA; hpB = hnB;

    // S5) publish h(s+1) with embedded mark, or final output
    if (s == 511){
      const int i0 = (g*16 + tr)*256 + hc;
      if (md){ ((float*)outv)[i0] = hnA; ((float*)outv)[i0 + 8*256] = hnB; }
      else   { ((u16*)outv)[i0] = f2bf(hnA); ((u16*)outv)[i0 + 8*256] = f2bf(hnB); }
    } else {
      const u32 sm = (u32)(((s + 1) >> 1) & 1);
      u32* hb2 = hgp + (unsigned)(par^1)*32768u + (unsigned)g*4096u;
      #pragma unroll
      for (int u=0; u<2; ++u){
        const float hn = u ? hnB : hnA;
        const u32 bh = f2bf(hn);
        u32 bl = f2bf(hn - bf2f((u16)bh));
        bl = (bl & ~1u) | sm;                 // steal lo LSB for the step-mark
        __hip_atomic_store(hb2 + (tr + u*8)*256 + hc, (bh << 16) | bl,
                           __ATOMIC_RELAXED, __HIP_MEMORY_SCOPE_AGENT);
      }
      // xw(s+1) -> other LDS buffer
      *(f32x4*)&xwlds[par^1][row1][gg1*64 + cc1*4] = n1;
      if (two) *(f32x4*)&xwlds[par^1][row2][gg2*64 + cc2*4] = n2;
    }
  }
}

extern "C" void kernel_launch(void* const* d_in, const int* in_sizes, int n_in,
                              void* d_out, int out_size, void* d_ws, size_t ws_size,
                              hipStream_t stream){
  const int* X = (const int*)d_in[0];
  char* ws = (char*)d_ws;
  if (ws_size < WS_NEED) return;

  k_init <<<256, 256, 0, stream>>>(ws);
  k_probe<<<  1,  64, 0, stream>>>(d_in[1], ws);
  k_wc   <<<320, 256, 0, stream>>>(d_in[2], d_in[4], d_in[6], d_in[8], d_in[10], ws);
  k_beff <<<  3, 256, 0, stream>>>(d_in[3], d_in[5], d_in[7], d_in[9], d_in[10], d_in[12], ws);
  k_embw <<<640, 256, 0, stream>>>(d_in[1], ws);
  k_whp  <<<768, 256, 0, stream>>>(d_in[11], ws);
  k_gru  <<< 32, 512, 0, stream>>>(X, d_in[13], ws, d_out);
}

// Round 22
// 2008.831 us; speedup vs baseline: 3.7367x; 1.0043x over previous
//
#include <hip/hip_runtime.h>
#include <hip/hip_bf16.h>

// ---------------------------------------------------------------------------
// CharRNN: emb -> 4x conv1d(SAME) -> concat -> GRU(256) last state.
//
// xw[b,t,:] = beff + sum_{d=0..4} EmbW[d][X[b,t+d-2]][:]   (f32 tables in ws)
//
// FINAL (R22): restore R14/R20 verbatim -- the session's verified optimum
// (2009/2017us total, k_gru ~1855us, absmax 9.8e-4). Eight structural
// attempts to beat its cross-XCD h-exchange latency floor failed (R12/R15:
// stale-L1 & InstCombine'd atomics; R16: RMW write storm; R17: barrier-
// coupled interleave; R18: spill wall; R19: async-LDS latency chain +
// bank conflicts; R21: loop-carried in-flight asm registers = rule-#18).
// Design:
//  - algebraic fold: emb+conv+Wx collapse to 5 table lookups/step (EmbW)
//  - runtime dtype probe (f32 vs bf16 storage) -> dtype-agnostic loads
//  - 32 blocks = 8 groups (16 batch rows) x 4 col-slices; Bf = 48 VGPRs
//  - h exchanged via ws as (hi<<16|lo) split-bf16 u32, step-mark in bit0
//    (self-validating, no flags); agent-scope relaxed atomics
//  - S1 probe: batched 2x global_load_dwordx4 sc0 sc1 + SSA-safe waitcnt
//  - 2 barriers/step; lane-parallel gates; split-bf16 h => ~f32 recurrence
// ---------------------------------------------------------------------------

typedef float f32x4 __attribute__((ext_vector_type(4)));
typedef short s16x8 __attribute__((ext_vector_type(8)));
typedef int   i32x4 __attribute__((ext_vector_type(4)));
typedef unsigned short u16;
typedef unsigned int   u32;
typedef unsigned long long u64;

// ws byte offsets
#define OFF_WC    0u         // f32  [5][64][768]
#define OFF_EMBW  983040u    // f32  [5][128][768]
#define OFF_BEFF  2949120u   // f32  [768]
#define OFF_WHP   2952192u   // bf16 [768][256] (Wh^T)
#define OFF_MODE  3345408u   // int
#define OFF_HGP   3345472u   // u32 [2][8][16][256]  (par, group, row, hcol)
#define WS_NEED   3607616u

__device__ __forceinline__ float bf2f(u16 v){
  unsigned u = ((unsigned)v) << 16; return __builtin_bit_cast(float, u);
}
__device__ __forceinline__ u16 f2bf(float f){
  unsigned u = __builtin_bit_cast(unsigned, f);
  unsigned r = u + 0x7FFFu + ((u >> 16) & 1u);
  return (u16)(r >> 16);
}
__device__ __forceinline__ float ldv(const void* p, int i, int m){
  return m ? ((const float*)p)[i] : bf2f(((const u16*)p)[i]);
}

// ---- init: zero both h parity planes (mark bits 0 -> steps 0,1 validate) ----
__global__ void k_init(char* ws){
  int idx = blockIdx.x*256 + threadIdx.x;
  u32* hg = (u32*)(ws + OFF_HGP);
  if (idx < 65536) hg[idx] = 0u;
}

// ---- probe: detect storage dtype of emb_table ----
__global__ void k_probe(const void* __restrict__ emb, char* ws){
  const u16* w = (const u16*)emb;
  const int ln = threadIdx.x;
  bool bad = false;
  for (int j = 0; j < 8; ++j){
    u16 v = w[ln*8 + j];
    if (((v >> 7) & 0xFF) >= 0x86) bad = true;
  }
  unsigned long long m = __ballot(bad);
  if (ln == 0) *(int*)(ws + OFF_MODE) = (__popcll(m) > 4) ? 1 : 0;
}

// ---- Wc[d][e][j] = sum_br sum_c w_br[d-2+pad][e][c] * Wx[off_br+c][j] ----
__global__ void k_wc(const void* __restrict__ w2, const void* __restrict__ w3,
                     const void* __restrict__ w4, const void* __restrict__ w5,
                     const void* __restrict__ Wx, char* ws){
  const int md = *(const int*)(ws + OFF_MODE);
  const int d = blockIdx.x >> 6;
  const int e = blockIdx.x & 63;
  const int j0 = threadIdx.x;
  const void* wv[4] = {w2,w3,w4,w5};
  const int Kk[4] = {2,3,4,5}, pd[4] = {0,1,1,2};
  float a0=0.f, a1=0.f, a2=0.f;
  for (int br=0; br<4; ++br){
    int k = d - 2 + pd[br];
    if (k < 0 || k >= Kk[br]) continue;
    const int wbase  = (k*64 + e)*128;
    const int wxbase = (br*128)*768;
    for (int c=0; c<128; ++c){
      float wcv = ldv(wv[br], wbase + c, md);
      a0 += wcv * ldv(Wx, wxbase + c*768 + j0      , md);
      a1 += wcv * ldv(Wx, wxbase + c*768 + j0 + 256, md);
      a2 += wcv * ldv(Wx, wxbase + c*768 + j0 + 512, md);
    }
  }
  float* o = (float*)(ws + OFF_WC) + (d*64 + e)*768;
  o[j0] = a0; o[j0+256] = a1; o[j0+512] = a2;
}

// ---- beff[j] = b_in[j] + sum_br sum_c b_br[c]*Wx[off+c][j] ----
__global__ void k_beff(const void* __restrict__ b2, const void* __restrict__ b3,
                       const void* __restrict__ b4, const void* __restrict__ b5,
                       const void* __restrict__ Wx, const void* __restrict__ bin,
                       char* ws){
  const int md = *(const int*)(ws + OFF_MODE);
  int j = blockIdx.x*256 + threadIdx.x;
  if (j >= 768) return;
  const void* bv[4] = {b2,b3,b4,b5};
  float acc = ldv(bin, j, md);
  for (int br=0; br<4; ++br)
    for (int c=0; c<128; ++c)
      acc += ldv(bv[br], c, md) * ldv(Wx, (br*128 + c)*768 + j, md);
  ((float*)(ws + OFF_BEFF))[j] = acc;
}

// ---- EmbW[d][ch][j] = sum_e emb[ch][e] * Wc[d][e][j]  (f32 out) ----
__global__ void k_embw(const void* __restrict__ emb, char* ws){
  const int md = *(const int*)(ws + OFF_MODE);
  const int d = blockIdx.x >> 7, ch = blockIdx.x & 127;
  const float* wc = (const float*)(ws + OFF_WC) + d*64*768;
  float* ew = (float*)(ws + OFF_EMBW) + (size_t)(d*128 + ch)*768;
  const int j0 = threadIdx.x;
  float a0=0.f, a1=0.f, a2=0.f;
  for (int e=0; e<64; ++e){
    float ev = ldv(emb, ch*64 + e, md);
    a0 += ev*wc[e*768 + j0      ];
    a1 += ev*wc[e*768 + j0 + 256];
    a2 += ev*wc[e*768 + j0 + 512];
  }
  ew[j0] = a0; ew[j0+256] = a1; ew[j0+512] = a2;
}

// ---- whp[j][k] = Wh[k][j]  (bf16 out) ----
__global__ void k_whp(const void* __restrict__ Wh, char* ws){
  const int md = *(const int*)(ws + OFF_MODE);
  const int j = blockIdx.x, k = threadIdx.x;
  ((u16*)(ws + OFF_WHP))[j*256 + k] = f2bf(ldv(Wh, k*768 + j, md));
}

// ---- GRU: 32 blocks = 8 groups x 4 slices; 512 thr / 8 waves ----
__launch_bounds__(512, 1)
__global__ void k_gru(const int* __restrict__ X, const void* __restrict__ brec,
                      char* __restrict__ ws, void* __restrict__ outv){
  const int tid = threadIdx.x;
  const int w   = tid >> 6, ln = tid & 63;
  const int l15 = ln & 15, l4 = ln >> 4;
  const int g = blockIdx.x >> 2, r = blockIdx.x & 3;

  const int md = *(const int*)(ws + OFF_MODE);
  const float* embw = (const float*)(ws + OFF_EMBW);
  const float* beff = (const float*)(ws + OFF_BEFF);
  const u16*   whp  = (const u16*)(ws + OFF_WHP);
  u32* hgp = (u32*)(ws + OFF_HGP);

  __shared__ int   Xs[16*512];           // 32 KB
  __shared__ float xwlds[2][16][196];    // 25 KB
  __shared__ float hwp[2][16][196];      // 25 KB
  __shared__ u16   hstage[2][16][272];   // 17 KB

  for (int i = tid; i < 2048; i += 512)
    ((i32x4*)Xs)[i] = ((const i32x4*)(X + g*16*512))[i];

  // persistent Wh B-frags: wave w -> subtile w&3, K-half w>>2
  const int qs = (w >> 2) * 4;
  s16x8 Bf[3][4];
  #pragma unroll
  for (int gg=0; gg<3; ++gg){
    const int col = gg*256 + r*64 + (w&3)*16 + l15;
    #pragma unroll
    for (int qi=0; qi<4; ++qi)
      Bf[gg][qi] = *(const s16x8*)(whp + col*256 + (qs+qi)*32 + l4*8);
  }

  // gates: thread -> h-col hc = r*64+(tid&63), rows tr, tr+8
  const int c63 = tid & 63;
  const int tr  = (tid >> 6) & 7;
  const int hc  = r*64 + c63;
  const float br0 = ldv(brec,       hc, md);
  const float br1 = ldv(brec, 256 + hc, md);
  const float br2 = ldv(brec, 512 + hc, md);

  // gather: chunk ids cid1 = tid, cid2 = tid+512 (tid<256 only)
  const int row1 = tid / 48,      rem1 = tid % 48;
  const int gg1  = rem1 / 16,     cc1  = rem1 % 16;
  const int cid2 = tid + 512;
  const int row2 = cid2 / 48,     rem2 = cid2 % 48;
  const int gg2  = rem2 / 16,     cc2  = rem2 % 16;
  const bool two = (tid < 256);
  const int gcol1 = gg1*256 + r*64 + cc1*4;
  const int gcol2 = gg2*256 + r*64 + cc2*4;
  const f32x4 be1 = *(const f32x4*)(beff + gcol1);
  const f32x4 be2 = *(const f32x4*)(beff + gcol2);

  // h-stage: thread -> row srow, 8 packed cols at sc0_
  const int srow = tid >> 5, sc0_ = (tid & 31) * 8;

  __syncthreads();   // Xs staged

  // prologue: xw(0) -> xwlds[0]
  {
    f32x4 v1 = be1, v2 = be2;
    #pragma unroll
    for (int d=0; d<5; ++d){
      const int t = d - 2;
      if ((unsigned)t < 512u){
        const int ch1 = Xs[row1*512 + t] & 127;
        v1 += *(const f32x4*)(embw + (size_t)(d*128 + ch1)*768 + gcol1);
        if (two){
          const int ch2 = Xs[row2*512 + t] & 127;
          v2 += *(const f32x4*)(embw + (size_t)(d*128 + ch2)*768 + gcol2);
        }
      }
    }
    *(f32x4*)&xwlds[0][row1][gg1*64 + cc1*4] = v1;
    if (two) *(f32x4*)&xwlds[0][row2][gg2*64 + cc2*4] = v2;
  }
  float hpA = 0.f, hpB = 0.f;
  __syncthreads();

  for (int s = 0; s < 512; ++s){
    const int par = s & 1;

    // S1) spin until this thread's 8 h-words are valid. Batched probe:
    //     2x global_load_dwordx4 (sc0 sc1) + ONE waitcnt carrying the
    //     tuples as "+v" -> consumers SSA-depend on the waitcnt asm.
    const u32 em = (u32)((s >> 1) & 1);
    const u32* hb = hgp + (unsigned)par*32768u + (unsigned)g*4096u
                    + (unsigned)srow*256u + (unsigned)sc0_;
    i32x4 A, B;
    {
      int guard = 0;
      for (;;){
        asm volatile("global_load_dwordx4 %0, %2, off sc0 sc1\n\t"
                     "global_load_dwordx4 %1, %3, off sc0 sc1"
                     : "=&v"(A), "=&v"(B)
                     : "v"(hb), "v"(hb + 4)
                     : "memory");
        asm volatile("s_waitcnt vmcnt(0)" : "+v"(A), "+v"(B) :: "memory");
        __builtin_amdgcn_sched_barrier(0);
        const u32 ba = (u32)A[0] & (u32)A[1] & (u32)A[2] & (u32)A[3]
                     & (u32)B[0] & (u32)B[1] & (u32)B[2] & (u32)B[3];
        const u32 bo = (u32)A[0] | (u32)A[1] | (u32)A[2] | (u32)A[3]
                     | (u32)B[0] | (u32)B[1] | (u32)B[2] | (u32)B[3];
        const bool ok = em ? ((ba & 1u) == 1u) : ((bo & 1u) == 0u);
        if (ok || ++guard > (1<<20)) break;   // guard: fail visibly, no hang
      }
    }
    // de-interleave word = (hi<<16) | lo  -> stage planes
    {
      u32 wd[8] = {(u32)A[0],(u32)A[1],(u32)A[2],(u32)A[3],
                   (u32)B[0],(u32)B[1],(u32)B[2],(u32)B[3]};
      s16x8 hi, lo;
      #pragma unroll
      for (int j=0; j<8; ++j){ hi[j] = (short)(wd[j] >> 16); lo[j] = (short)(wd[j] & 0xFFFFu); }
      *(s16x8*)&hstage[0][srow][sc0_] = hi;
      *(s16x8*)&hstage[1][srow][sc0_] = lo;
    }
    __syncthreads();                          // barA: stage ready

    // S2) partial hw over this wave's K-half: 24 MFMAs
    f32x4 a0 = {0.f,0.f,0.f,0.f}, a1 = a0, a2 = a0;
    #pragma unroll
    for (int qi=0; qi<4; ++qi){
      const int kb = (qs+qi)*32 + l4*8;
      const s16x8 ahi = *(const s16x8*)&hstage[0][l15][kb];
      const s16x8 alo = *(const s16x8*)&hstage[1][l15][kb];
      a0 = __builtin_amdgcn_mfma_f32_16x16x32_bf16(ahi, Bf[0][qi], a0, 0,0,0);
      a1 = __builtin_amdgcn_mfma_f32_16x16x32_bf16(ahi, Bf[1][qi], a1, 0,0,0);
      a2 = __builtin_amdgcn_mfma_f32_16x16x32_bf16(ahi, Bf[2][qi], a2, 0,0,0);
      a0 = __builtin_amdgcn_mfma_f32_16x16x32_bf16(alo, Bf[0][qi], a0, 0,0,0);
      a1 = __builtin_amdgcn_mfma_f32_16x16x32_bf16(alo, Bf[1][qi], a1, 0,0,0);
      a2 = __builtin_amdgcn_mfma_f32_16x16x32_bf16(alo, Bf[2][qi], a2, 0,0,0);
    }
    {
      const int kh = w >> 2, sc = (w&3)*16 + l15;
      #pragma unroll
      for (int p=0; p<4; ++p){
        hwp[kh][l4*4+p][       sc] = a0[p];
        hwp[kh][l4*4+p][ 64 + sc] = a1[p];
        hwp[kh][l4*4+p][128 + sc] = a2[p];
      }
    }

    // S3) gather xw(s+1): issue now (L2 latency hides until gates consume)
    f32x4 n1, n2;
    if (s < 511){
      n1 = be1; n2 = be2;
      #pragma unroll
      for (int d=0; d<5; ++d){
        const int t = s - 1 + d;
        if ((unsigned)t < 512u){
          const int ch1 = Xs[row1*512 + t] & 127;
          n1 += *(const f32x4*)(embw + (size_t)(d*128 + ch1)*768 + gcol1);
          if (two){
            const int ch2 = Xs[row2*512 + t] & 127;
            n2 += *(const f32x4*)(embw + (size_t)(d*128 + ch2)*768 + gcol2);
          }
        }
      }
    }
    __syncthreads();                          // barB: hwp ready

    // S4) gates for units (tr, hc) and (tr+8, hc)
    float hnA, hnB;
    #pragma unroll
    for (int u=0; u<2; ++u){
      const int row = tr + u*8;
      const float hz = hwp[0][row][      c63] + hwp[1][row][      c63] + br0;
      const float hr = hwp[0][row][ 64 + c63] + hwp[1][row][ 64 + c63] + br1;
      const float hh = hwp[0][row][128 + c63] + hwp[1][row][128 + c63] + br2;
      const float xz = xwlds[par][row][      c63];
      const float xr = xwlds[par][row][ 64 + c63];
      const float xh = xwlds[par][row][128 + c63];
      const float hp = u ? hpB : hpA;
      const float z  = 1.f/(1.f + __expf(-(xz + hz)));
      const float rg = 1.f/(1.f + __expf(-(xr + hr)));
      const float pre = xh + rg*hh;
      const float e2  = __expf(-2.f*fabsf(pre));
      const float th  = __builtin_copysignf((1.f - e2)/(1.f + e2), pre);
      const float hn  = z*hp + (1.f - z)*th;
      if (u) hnB = hn; else hnA = hn;
    }
    hpA = hnA; hpB = hnB;

    // S5) publish h(s+1) with embedded mark, or final output
    if (s == 511){
      const int i0 = (g*16 + tr)*256 + hc;
      if (md){ ((float*)outv)[i0] = hnA; ((float*)outv)[i0 + 8*256] = hnB; }
      else   { ((u16*)outv)[i0] = f2bf(hnA); ((u16*)outv)[i0 + 8*256] = f2bf(hnB); }
    } else {
      const u32 sm = (u32)(((s + 1) >> 1) & 1);
      u32* hb2 = hgp + (unsigned)(par^1)*32768u + (unsigned)g*4096u;
      #pragma unroll
      for (int u=0; u<2; ++u){
        const float hn = u ? hnB : hnA;
        const u32 bh = f2bf(hn);
        u32 bl = f2bf(hn - bf2f((u16)bh));
        bl = (bl & ~1u) | sm;                 // steal lo LSB for the step-mark
        __hip_atomic_store(hb2 + (tr + u*8)*256 + hc, (bh << 16) | bl,
                           __ATOMIC_RELAXED, __HIP_MEMORY_SCOPE_AGENT);
      }
      // xw(s+1) -> other LDS buffer
      *(f32x4*)&xwlds[par^1][row1][gg1*64 + cc1*4] = n1;
      if (two) *(f32x4*)&xwlds[par^1][row2][gg2*64 + cc2*4] = n2;
    }
  }
}

extern "C" void kernel_launch(void* const* d_in, const int* in_sizes, int n_in,
                              void* d_out, int out_size, void* d_ws, size_t ws_size,
                              hipStream_t stream){
  const int* X = (const int*)d_in[0];
  char* ws = (char*)d_ws;
  if (ws_size < WS_NEED) return;

  k_init <<<256, 256, 0, stream>>>(ws);
  k_probe<<<  1,  64, 0, stream>>>(d_in[1], ws);
  k_wc   <<<320, 256, 0, stream>>>(d_in[2], d_in[4], d_in[6], d_in[8], d_in[10], ws);
  k_beff <<<  3, 256, 0, stream>>>(d_in[3], d_in[5], d_in[7], d_in[9], d_in[10], d_in[12], ws);
  k_embw <<<640, 256, 0, stream>>>(d_in[1], ws);
  k_whp  <<<768, 256, 0, stream>>>(d_in[11], ws);
  k_gru  <<< 32, 512, 0, stream>>>(X, d_in[13], ws, d_out);
}